// Round 14
// baseline (1460.665 us; speedup 1.0000x reference)
//
#include <hip/hip_runtime.h>
#include <math.h>

#define T_STEPS 128
#define B_SZ 128
#define D_SZ 1024
#define H_SZ 1024
#define G4 4096
#define KW 2048  // rows of W = D+H

typedef __attribute__((ext_vector_type(8))) short bf16x8;
typedef __attribute__((ext_vector_type(4))) float f32x4;
typedef unsigned short ushort_t;
typedef unsigned int uint_t;
typedef unsigned long long ull_t;

__device__ __forceinline__ float sigf(float x) { return 1.0f / (1.0f + __expf(-x)); }
__device__ __forceinline__ float tanhfast(float x) { return 1.0f - 2.0f * sigf(-2.0f * x); }

__device__ __forceinline__ ushort_t f2bf(float f) {
  uint_t u = __float_as_uint(f);
  return (ushort_t)((u + 0x7fffu + ((u >> 16) & 1u)) >> 16);
}
__device__ __forceinline__ float bf2f(ushort_t s) {
  return __uint_as_float(((uint_t)s) << 16);
}

#define GLOAD_LDS16(gp, lp)                                                  \
  __builtin_amdgcn_global_load_lds(                                          \
      (const __attribute__((address_space(1))) unsigned int*)(const void*)(gp), \
      (__attribute__((address_space(3))) unsigned int*)(void*)(lp), 16, 0, 0)

// ---------------------------------------------------------------------------
// x fp32 [16384][1024] -> bf16 same layout. 8 elems/thread.
// ---------------------------------------------------------------------------
__global__ __launch_bounds__(256) void convert_x(const float* __restrict__ x,
                                                 ushort_t* __restrict__ xbf) {
  const size_t i8 = ((size_t)blockIdx.x * 256 + threadIdx.x) * 8;
  if (i8 + 8 > (size_t)T_STEPS * B_SZ * D_SZ) return;
  float4 a = *(const float4*)&x[i8];
  float4 b = *(const float4*)&x[i8 + 4];
  ushort_t o[8] = {f2bf(a.x), f2bf(a.y), f2bf(a.z), f2bf(a.w),
                   f2bf(b.x), f2bf(b.y), f2bf(b.z), f2bf(b.w)};
  *(uint4*)&xbf[i8] = *(uint4*)o;
}

// ---------------------------------------------------------------------------
// W fp32 [2048][4096] -> WT bf16 [4096][2048]  (WT[n][k] = W[k][n])
// ---------------------------------------------------------------------------
__global__ __launch_bounds__(256) void transpose_w(const float* __restrict__ W,
                                                   ushort_t* __restrict__ WT) {
  __shared__ float t[32][33];
  const int tx = threadIdx.x & 31;
  const int ty = threadIdx.x >> 5;  // 0..7
  const int k0 = blockIdx.x * 32;
  const int n0 = blockIdx.y * 32;
#pragma unroll
  for (int i = 0; i < 4; ++i)
    t[ty + i * 8][tx] = W[(size_t)(k0 + ty + i * 8) * G4 + n0 + tx];
  __syncthreads();
#pragma unroll
  for (int i = 0; i < 4; ++i)
    WT[(size_t)(n0 + ty + i * 8) * KW + k0 + tx] = f2bf(t[tx][ty + i * 8]);
}

// ---------------------------------------------------------------------------
// hbf0 = bf16(h0 * (1-reset[0]))
// ---------------------------------------------------------------------------
__global__ __launch_bounds__(256) void init_state(const float* __restrict__ h0,
                                                  const float* __restrict__ reset0,
                                                  ushort_t* __restrict__ hbf0) {
  const int i = blockIdx.x * 256 + threadIdx.x;
  if (i >= B_SZ * H_SZ) return;
  hbf0[i] = f2bf(h0[i] * (1.0f - reset0[i >> 10]));
}

// ---------------------------------------------------------------------------
// Fused persistent LSTM. 256 blocks (1/CU) x 512 thr.
// Block (jt=bid&63, btp=bid>>6): rows [btp*32,+32) x cols [jt*16,+16), all 4
// gates. 4 independent groups of 64 blocks; per-group own-word sync (R10).
// NEW (v8): the x-part GEMM is fused INTO the step loop — each block computes
// its own 4KB xw slice for step t+1 during the otherwise-idle sync window
// (after arrive, before poll): A = xbf rows staged into Ah (freed by rGEMM,
// flight hidden under elem/drain), B = 128KB Wx slice streamed from L2
// (8 jt/XCD -> 1MB, L2-hot), acc init = bias (same accumulation order as the
// old xw kernel). Result lives in an 8KB LDS buffer; xwg global traffic
// (134MB write + 134MB read) and the separate 95us xw kernel are eliminated.
// Wh resident: k[1024,1536) in LDS (swizzled), k[1536,2048) in 16 VGPR frags.
// ---------------------------------------------------------------------------
__global__ __launch_bounds__(512) void lstm_persist8(
    const ushort_t* __restrict__ hbf0,  // [128][1024] premasked bf16
    const float* __restrict__ c0,       // [128][1024] raw
    const float* __restrict__ reset,    // [T][128]
    const ushort_t* __restrict__ xbf,   // [T*128][1024] bf16
    const ushort_t* __restrict__ WT,    // [4096][2048]
    const float* __restrict__ bias,     // [4096]
    float* __restrict__ out,            // [T*128][1024] then hT, cT
    ushort_t* __restrict__ hring,       // [T][128][1024] premasked bf16 ring
    uint_t* __restrict__ bar)           // [4][256] arrival words, zeroed
{
  __shared__ ushort_t WhL[64 * 512];   // 64 KB  Wh k-half, swizzled
  __shared__ ushort_t Ah[32 * 1024];   // 64 KB  shared h/x staging, swizzled
  __shared__ float sc[2][4][16][17];   // 8.7 KB rGEMM split combine
  __shared__ ushort_t xwL[4][32][16];  // 8 KB   local xw slice (bias incl.)

  const int tid = threadIdx.x;
  const int bid = blockIdx.x;   // 0..255
  const int jt = bid & 63;
  const int btp = bid >> 6;     // 0..3 = batch-group
  const int b0 = btp * 32;
  const int lane = tid & 63;
  const int wid = tid >> 6;     // 0..7
  const int gw = wid & 3;
  const int mh = wid >> 2;
  const int lr = lane & 15;
  const int ko = lane >> 4;
  const size_t SE = (size_t)B_SZ * H_SZ;

  uint_t* const arr = bar + btp * 256;

  // ---- stage WhL: k in [1024,1536) (once) ----
  for (int q = 0; q < 8; ++q) {
    const int id = q * 512 + tid;
    const int wrw = id >> 6;
    const int kb = (id & 63) * 16;
    const int n = (wrw >> 4) * H_SZ + jt * 16 + (wrw & 15);
    const uint4 v = *(const uint4*)((const char*)WT + (size_t)n * 4096 + 2048 + kb);
    *(uint4*)((char*)WhL + wrw * 1024 + (kb ^ ((wrw & 7) << 4))) = v;
  }
  // ---- breg: Wh k in [1536,2048) for wave's gate ----
  const char* wrow = (const char*)WT + (size_t)(gw * H_SZ + jt * 16 + lr) * 4096;
  bf16x8 breg[16];
#pragma unroll
  for (int q = 0; q < 16; ++q)
    breg[q] = *(const bf16x8*)(wrow + 3072 + q * 64 + ko * 16);

  // bias as xGEMM acc-init (same j-col for all 4 acc rows)
  const float bias_n = bias[gw * H_SZ + jt * 16 + lr];
  const f32x4 bias4 = {bias_n, bias_n, bias_n, bias_n};

  // ---- per-thread output element state ----
  const int row = tid >> 4;     // 0..31
  const int col = tid & 15;
  const int b = b0 + row;
  const int j = jt * 16 + col;
  const size_t so = (size_t)b * H_SZ + j;
  float creg = c0[so] * (1.0f - reset[b]);
  float mn = 1.0f - reset[B_SZ + b];  // mask for t=1

  const int swzl = (lr & 7) << 4;
  const char* aBase = (const char*)Ah + (mh * 16 + lr) * 2048;
  const char* bBase = (const char*)WhL + (gw * 16 + lr) * 1024;
  const char* xbB = (const char*)WT + (size_t)(gw * H_SZ + jt * 16 + lr) * 4096;  // Wx row

#define STAGE_A(SRCB)                                                          \
  {                                                                            \
    _Pragma("unroll") for (int i = 0; i < 8; ++i) {                            \
      const int cc = wid * 8 + i;                                              \
      const int ar = cc >> 1;                                                  \
      const int hf = (cc & 1) * 1024;                                          \
      const int kb = hf + lane * 16;                                           \
      GLOAD_LDS16((SRCB) + (size_t)ar * 2048 + (kb ^ ((ar & 7) << 4)),         \
                  (char*)Ah + ar * 2048 + hf);                                 \
    }                                                                          \
  }

#define XGEMM_TO_XWL()                                                         \
  {                                                                            \
    f32x4 xacc = bias4;                                                        \
    _Pragma("unroll") for (int ks = 0; ks < 32; ++ks) {                        \
      bf16x8 a = *(const bf16x8*)(aBase + ((ks * 64 + ko * 16) ^ swzl));       \
      bf16x8 bx = *(const bf16x8*)(xbB + ks * 64 + ko * 16);                   \
      xacc = __builtin_amdgcn_mfma_f32_16x16x32_bf16(a, bx, xacc, 0, 0, 0);    \
    }                                                                          \
    _Pragma("unroll") for (int r = 0; r < 4; ++r)                              \
        xwL[gw][mh * 16 + ko * 4 + r][lr] = f2bf(xacc[r]);                     \
  }

  // ---- prologue: xwL(0) from xbf rows (t=0, btp) ----
  STAGE_A((const char*)xbf + (size_t)b0 * 2048);
  __syncthreads();
  XGEMM_TO_XWL();
  __syncthreads();  // xwL(0) ready; Ah free

  float* const hT = out + (size_t)T_STEPS * SE;
  float* const cT = hT + SE;

  for (int t = 0; t < T_STEPS; ++t) {
    // ---- poll peers (wave 0) + broadcast ----
    if (t > 0) {
      if (wid == 0) {
        uint_t it = 0;
        for (;;) {
          const uint_t v = __hip_atomic_load(&arr[lane], __ATOMIC_RELAXED,
                                             __HIP_MEMORY_SCOPE_AGENT);
          if (__all((int)v >= t)) break;
          __builtin_amdgcn_s_sleep(1);
          if (++it > 1000000u) break;  // bounded: fail visibly, don't hang
        }
      }
      __syncthreads();  // #0
    }
    // ---- stage h(t) -> Ah ----
    const char* hb = (t == 0) ? (const char*)hbf0
                              : (const char*)(hring + (size_t)t * SE);
    STAGE_A(hb + (size_t)b0 * 2048);
    __syncthreads();  // #1 (compiler drains vmcnt before barrier)

    // ---- rGEMM: 16x16 per wave, K=1024, 4 independent chains ----
    f32x4 ac0 = {}, ac1 = {}, ac2 = {}, ac3 = {};
#pragma unroll
    for (int q = 0; q < 4; ++q) {
      bf16x8 a0 = *(const bf16x8*)(aBase + (((q * 4 + 0) * 64 + ko * 16) ^ swzl));
      bf16x8 b0f = *(const bf16x8*)(bBase + (((q * 4 + 0) * 64 + ko * 16) ^ swzl));
      ac0 = __builtin_amdgcn_mfma_f32_16x16x32_bf16(a0, b0f, ac0, 0, 0, 0);
      bf16x8 a1 = *(const bf16x8*)(aBase + (((q * 4 + 1) * 64 + ko * 16) ^ swzl));
      bf16x8 b1f = *(const bf16x8*)(bBase + (((q * 4 + 1) * 64 + ko * 16) ^ swzl));
      ac1 = __builtin_amdgcn_mfma_f32_16x16x32_bf16(a1, b1f, ac1, 0, 0, 0);
      bf16x8 a2 = *(const bf16x8*)(aBase + (((q * 4 + 2) * 64 + ko * 16) ^ swzl));
      bf16x8 b2f = *(const bf16x8*)(bBase + (((q * 4 + 2) * 64 + ko * 16) ^ swzl));
      ac2 = __builtin_amdgcn_mfma_f32_16x16x32_bf16(a2, b2f, ac2, 0, 0, 0);
      bf16x8 a3 = *(const bf16x8*)(aBase + (((q * 4 + 3) * 64 + ko * 16) ^ swzl));
      bf16x8 b3f = *(const bf16x8*)(bBase + (((q * 4 + 3) * 64 + ko * 16) ^ swzl));
      ac3 = __builtin_amdgcn_mfma_f32_16x16x32_bf16(a3, b3f, ac3, 0, 0, 0);
    }
#pragma unroll
    for (int q = 0; q < 4; ++q) {
      bf16x8 a0 = *(const bf16x8*)(aBase + (((16 + q * 4 + 0) * 64 + ko * 16) ^ swzl));
      ac0 = __builtin_amdgcn_mfma_f32_16x16x32_bf16(a0, breg[q * 4 + 0], ac0, 0, 0, 0);
      bf16x8 a1 = *(const bf16x8*)(aBase + (((16 + q * 4 + 1) * 64 + ko * 16) ^ swzl));
      ac1 = __builtin_amdgcn_mfma_f32_16x16x32_bf16(a1, breg[q * 4 + 1], ac1, 0, 0, 0);
      bf16x8 a2 = *(const bf16x8*)(aBase + (((16 + q * 4 + 2) * 64 + ko * 16) ^ swzl));
      ac2 = __builtin_amdgcn_mfma_f32_16x16x32_bf16(a2, breg[q * 4 + 2], ac2, 0, 0, 0);
      bf16x8 a3 = *(const bf16x8*)(aBase + (((16 + q * 4 + 3) * 64 + ko * 16) ^ swzl));
      ac3 = __builtin_amdgcn_mfma_f32_16x16x32_bf16(a3, breg[q * 4 + 3], ac3, 0, 0, 0);
    }
    const f32x4 acc = (ac0 + ac1) + (ac2 + ac3);
#pragma unroll
    for (int r = 0; r < 4; ++r) sc[mh][gw][ko * 4 + r][lr] = acc[r];
    __syncthreads();  // #2 (sc ready; Ah free for x-stage)

    // ---- stage x(t+1) -> Ah; flight hides under elem + drain ----
    if (t + 1 < T_STEPS)
      STAGE_A((const char*)xbf + ((size_t)(t + 1) * B_SZ + b0) * 2048);

    // ---- fused elementwise: 512 threads -> 32 rows x 16 cols ----
    const float gi = sc[row >> 4][0][row & 15][col] + bf2f(xwL[0][row][col]);
    const float gg = sc[row >> 4][1][row & 15][col] + bf2f(xwL[1][row][col]);
    const float gf = sc[row >> 4][2][row & 15][col] + bf2f(xwL[2][row][col]);
    const float go = sc[row >> 4][3][row & 15][col] + bf2f(xwL[3][row][col]);
    const float f = sigf(gf + 1.0f);
    const float cn = f * creg + sigf(gi) * tanhfast(gg);
    const float hn = sigf(go) * tanhfast(cn);
    creg = cn * mn;

    if (t < T_STEPS - 1) {
      // pack 4 neighboring cols' h into one 8B sc-store (128 stores/block)
      const uint_t hm = (uint_t)f2bf(hn * mn);
      const uint_t h1 = (uint_t)__shfl_down((int)hm, 1);
      const uint_t h2 = (uint_t)__shfl_down((int)hm, 2);
      const uint_t h3 = (uint_t)__shfl_down((int)hm, 3);
      if ((col & 3) == 0) {
        const ull_t pk = (ull_t)(hm & 0xffffu) | ((ull_t)(h1 & 0xffffu) << 16) |
                         ((ull_t)(h2 & 0xffffu) << 32) | ((ull_t)(h3 & 0xffffu) << 48);
        __hip_atomic_store((ull_t*)(hring + (size_t)(t + 1) * SE + so), pk,
                           __ATOMIC_RELAXED, __HIP_MEMORY_SCOPE_AGENT);
      }
    } else {
      hT[so] = hn;
      cT[so] = cn;  // unmasked at last step
    }
    asm volatile("s_waitcnt vmcnt(0)" ::: "memory");  // drain h-stores + x-stage
    __syncthreads();  // #3 (h drained block-wide; Ah = x(t+1) landed)

    if (tid == 0 && t < T_STEPS - 1)
      __hip_atomic_store(&arr[jt], (uint_t)(t + 1), __ATOMIC_RELAXED,
                         __HIP_MEMORY_SCOPE_AGENT);
    out[(size_t)t * SE + so] = hn;

    if (t < T_STEPS - 1) {
      mn = (t + 1 < T_STEPS - 1) ? (1.0f - reset[(size_t)(t + 2) * B_SZ + b]) : 1.0f;
      // ---- xGEMM(t+1) in the sync window: A = Ah (x rows), B = Wx (L2) ----
      XGEMM_TO_XWL();
    }
  }
}

extern "C" void kernel_launch(void* const* d_in, const int* in_sizes, int n_in,
                              void* d_out, int out_size, void* d_ws, size_t ws_size,
                              hipStream_t stream) {
  (void)in_sizes; (void)n_in; (void)out_size; (void)ws_size;
  const float* x = (const float*)d_in[0];
  const float* h0 = (const float*)d_in[1];
  const float* c0 = (const float*)d_in[2];
  const float* reset = (const float*)d_in[3];
  const float* W = (const float*)d_in[4];
  const float* bias = (const float*)d_in[5];
  float* out = (float*)d_out;

  const size_t TB = (size_t)T_STEPS * B_SZ;  // 16384
  const size_t SE = (size_t)B_SZ * H_SZ;     // 131072

  // ws layout (~84 MB; xwg eliminated)
  char* p = (char*)d_ws;
  uint_t* bar = (uint_t*)p;               p += 16384;
  ushort_t* WT = (ushort_t*)p;            p += (size_t)G4 * KW * 2;       // 16.8MB
  ushort_t* xbf = (ushort_t*)p;           p += TB * D_SZ * 2;             // 33.6MB
  ushort_t* hbf0 = (ushort_t*)p;          p += SE * 2;                    // 0.26MB
  ushort_t* hring = (ushort_t*)p;         p += (size_t)T_STEPS * SE * 2;  // 33.6MB

  hipMemsetAsync(bar, 0, 16384, stream);
  convert_x<<<dim3((int)(TB * D_SZ / 8 / 256)), 256, 0, stream>>>(x, xbf);
  transpose_w<<<dim3(KW / 32, G4 / 32), 256, 0, stream>>>(W, WT);
  init_state<<<dim3((int)((SE + 255) / 256)), 256, 0, stream>>>(h0, reset, hbf0);

  lstm_persist8<<<dim3(256), 512, 0, stream>>>(hbf0, c0, reset, xbf, WT, bias,
                                               out, hring, bar);
}